// Round 1
// baseline (405.079 us; speedup 1.0000x reference)
//
#include <hip/hip_runtime.h>
#include <cstdint>
#include <cstddef>

// ---------------------------------------------------------------------------
// SpaceSelfAttentionModality on MI355X (gfx950)
// Pipeline: cvt(x) -> transpose-cvt(W) -> QKV GEMM (bf16 MFMA) -> flash attn
//           with modality-mask tile skipping -> output-proj GEMM -> f32 out.
// ---------------------------------------------------------------------------

#define BT_N    8
#define SEQ_N   1024
#define DMODEL  1024
#define NHEADS  16
#define HDIM    64
#define NLAT    64

typedef __attribute__((ext_vector_type(4))) float f32x4;
typedef __attribute__((ext_vector_type(8))) __bf16 bf16x8;
typedef __attribute__((ext_vector_type(4))) short short4v;
typedef __attribute__((ext_vector_type(8))) short short8v;

__device__ __forceinline__ short f2bf(float f) {
  union { float f; unsigned u; } x; x.f = f;
  unsigned r = x.u + 0x7fffu + ((x.u >> 16) & 1u);   // RNE (no NaN inputs here)
  return (short)(r >> 16);
}

#define GLOAD_LDS16(gsrc, ldst)                                                   \
  __builtin_amdgcn_global_load_lds(                                               \
      (const __attribute__((address_space(1))) void*)(gsrc),                      \
      (__attribute__((address_space(3))) void*)(ldst), 16, 0, 0)

#define MFMA16(a, b, c) __builtin_amdgcn_mfma_f32_16x16x32_bf16((a), (b), (c), 0, 0, 0)

// ---------------------------------------------------------------------------
// Kernel 1: plain f32 -> bf16 convert (vectorized float4 -> 4x bf16)
// ---------------------------------------------------------------------------
__global__ __launch_bounds__(256)
void cvt_plain(const float* __restrict__ in, short* __restrict__ out, int n4) {
  int i = blockIdx.x * 256 + threadIdx.x;
  if (i >= n4) return;
  float4 f = reinterpret_cast<const float4*>(in)[i];
  short4v o;
  o.x = f2bf(f.x); o.y = f2bf(f.y); o.z = f2bf(f.z); o.w = f2bf(f.w);
  reinterpret_cast<short4v*>(out)[i] = o;
}

// ---------------------------------------------------------------------------
// Kernel 2: 1024x1024 f32 -> transposed bf16 (out[c][r] = in[r][c]),
// LDS-tiled 64x64 so both global sides are coalesced.
// ---------------------------------------------------------------------------
__global__ __launch_bounds__(256)
void cvt_T(const float* __restrict__ in, short* __restrict__ out) {
  __shared__ short t[64][65];
  int tc = blockIdx.x * 64, tr = blockIdx.y * 64;
  int lx = threadIdx.x & 63, ly = threadIdx.x >> 6;  // ly in 0..3
#pragma unroll
  for (int i = 0; i < 16; ++i) {
    int r = ly + i * 4;
    t[r][lx] = f2bf(in[(size_t)(tr + r) * 1024 + tc + lx]);
  }
  __syncthreads();
#pragma unroll
  for (int i = 0; i < 16; ++i) {
    int c = ly + i * 4;
    out[(size_t)(tc + c) * 1024 + tr + lx] = t[lx][c];
  }
}

// ---------------------------------------------------------------------------
// Kernel 3/5: bf16 GEMM, C = A[M x 1024] * Bt[N x 1024]^T.
// 128x128 tile, BK=64, 256 threads (4 waves, 2x2), double-buffered
// global_load_lds (width 16) staging, 16x16x32 bf16 MFMA, 4x4 frags/wave.
// MODE 0: QKV epilogue (bias, q-scale, scatter to [bt][h][s][d] bf16).
// MODE 1: proj epilogue (add bo, f32 row-major out).
// ---------------------------------------------------------------------------
template <int MODE>
__global__ __launch_bounds__(256, 2)
void gemm_bf16(const short* __restrict__ A, const short* __restrict__ Bt,
               const float* __restrict__ bq, const float* __restrict__ bk,
               const float* __restrict__ bv, short* __restrict__ qkv_out,
               const float* __restrict__ bo, float* __restrict__ out) {
  __shared__ __align__(16) short sA[2][128 * 64];
  __shared__ __align__(16) short sB[2][128 * 64];
  const int tid = threadIdx.x;
  const int l = tid & 63, w = tid >> 6;
  const int wr = w >> 1, wc = w & 1;
  const int lg = l >> 4, li = l & 15;
  const int m0 = blockIdx.y * 128, n0 = blockIdx.x * 128;

  f32x4 acc[4][4] = {};

  auto stage = [&](int buf, int kt) {
    const int kb = kt * 64;
#pragma unroll
    for (int i = 0; i < 4; ++i) {
      int ch = tid + 256 * i;        // 0..1023, 16B chunks
      int r = ch >> 3, c = ch & 7;
      GLOAD_LDS16(A + (size_t)(m0 + r) * 1024 + kb + c * 8, &sA[buf][ch * 8]);
    }
#pragma unroll
    for (int i = 0; i < 4; ++i) {
      int ch = tid + 256 * i;
      int r = ch >> 3, c = ch & 7;
      GLOAD_LDS16(Bt + (size_t)(n0 + r) * 1024 + kb + c * 8, &sB[buf][ch * 8]);
    }
  };

  stage(0, 0);
  __syncthreads();                    // drains vmcnt before first compute
  const int NK = 1024 / 64;
  for (int kt = 0; kt < NK; ++kt) {
    const int cur = kt & 1;
    if (kt + 1 < NK) stage(cur ^ 1, kt + 1);
#pragma unroll
    for (int kk = 0; kk < 64; kk += 32) {
      bf16x8 af[4], bfr[4];
#pragma unroll
      for (int mi = 0; mi < 4; ++mi)
        af[mi] = *(const bf16x8*)&sA[cur][(wr * 64 + mi * 16 + li) * 64 + kk + lg * 8];
#pragma unroll
      for (int ni = 0; ni < 4; ++ni)
        bfr[ni] = *(const bf16x8*)&sB[cur][(wc * 64 + ni * 16 + li) * 64 + kk + lg * 8];
#pragma unroll
      for (int mi = 0; mi < 4; ++mi)
#pragma unroll
        for (int ni = 0; ni < 4; ++ni)
          acc[mi][ni] = MFMA16(af[mi], bfr[ni], acc[mi][ni]);
    }
    __syncthreads();                  // drains vmcnt (stage) + protects buffers
  }

  // Epilogue. C/D layout: col = lane&15, row = (lane>>4)*4 + reg  [m89-verified]
  if (MODE == 0) {
#pragma unroll
    for (int ni = 0; ni < 4; ++ni) {
      const int n = n0 + wc * 64 + ni * 16 + li;  // 0..3071
      const int which = n >> 10;                  // 0=q 1=k 2=v
      const int hd_idx = n & 1023;
      const float* bias = (which == 0) ? bq : ((which == 1) ? bk : bv);
      const float bval = bias[hd_idx];
      const int h = hd_idx >> 6, d = hd_idx & 63;
      short* dst = qkv_out + (size_t)which * (BT_N * NHEADS * SEQ_N * HDIM);
#pragma unroll
      for (int mi = 0; mi < 4; ++mi) {
#pragma unroll
        for (int reg = 0; reg < 4; ++reg) {
          const int m = m0 + wr * 64 + mi * 16 + lg * 4 + reg;
          const int bt = m >> 10, s = m & 1023;
          float v = acc[mi][ni][reg] + bval;
          if (which == 0) v *= 0.125f;            // 1/sqrt(64)
          dst[(((size_t)(bt * NHEADS + h)) * SEQ_N + s) * HDIM + d] = f2bf(v);
        }
      }
    }
  } else {
#pragma unroll
    for (int ni = 0; ni < 4; ++ni) {
      const int n = n0 + wc * 64 + ni * 16 + li;
      const float bval = bo[n];
#pragma unroll
      for (int mi = 0; mi < 4; ++mi) {
#pragma unroll
        for (int reg = 0; reg < 4; ++reg) {
          const int m = m0 + wr * 64 + mi * 16 + lg * 4 + reg;
          out[(size_t)m * 1024 + n] = acc[mi][ni][reg] + bval;
        }
      }
    }
  }
}

// ---------------------------------------------------------------------------
// Kernel 4: flash attention with modality mask + tile skipping.
// Grid (S/64, H, BT), 256 threads = 4 waves; wave w owns q rows [qb+16w, +16).
// K-tile = 64. K staged via global_load_lds with XOR-swizzled SOURCE (rule 21);
// V staged transposed (reg->LDS) with the same chunk swizzle; P goes through a
// per-wave swizzled LDS buffer to become the PV A-fragment.
// ---------------------------------------------------------------------------
__global__ __launch_bounds__(256, 3)
void attn_kernel(const short* __restrict__ qg, const short* __restrict__ kg,
                 const short* __restrict__ vg, const int* __restrict__ ids,
                 short* __restrict__ ao) {
  __shared__ __align__(16) short sK[64 * 64];
  __shared__ __align__(16) short sV[64 * 64];     // V^T, swizzled
  __shared__ __align__(16) short sP[4][16 * 64];  // per-wave P, swizzled
  __shared__ int sid[SEQ_N];
  __shared__ int need[16];

  const int tid = threadIdx.x;
  const int l = tid & 63, w = tid >> 6;
  const int lg = l >> 4, li = l & 15;
  const int qt = blockIdx.x, h = blockIdx.y, bt = blockIdx.z;
  const int qb = qt * 64;
  const size_t hb = ((size_t)(bt * NHEADS + h)) * SEQ_N * HDIM;

  for (int i = tid; i < SEQ_N; i += 256) sid[i] = ids[i];
  if (tid < 16) need[tid] = 0;
  __syncthreads();
  {
    // tile t needed iff any (q in block, s in tile) allowed
    const int t = tid >> 4, j = tid & 15;
    bool any = (qb < NLAT);                        // latent q rows attend all
    if (!any) {
#pragma unroll
      for (int ss = 0; ss < 4; ++ss) {
        const int sv = sid[t * 64 + j * 4 + ss];
        for (int r = 0; r < 64; ++r) any |= (sid[qb + r] == sv);
      }
    }
    if (any) need[t] = 1;
  }
  __syncthreads();

  // Q fragments (rows qb+16w .. +16), already scaled by 1/8 at projection
  const bf16x8 qf0 = *(const bf16x8*)(qg + hb + (size_t)(qb + w * 16 + li) * HDIM + lg * 8);
  const bf16x8 qf1 = *(const bf16x8*)(qg + hb + (size_t)(qb + w * 16 + li) * HDIM + 32 + lg * 8);
  int qid[4]; bool lat[4]; float mrun[4], lrun[4];
#pragma unroll
  for (int reg = 0; reg < 4; ++reg) {
    const int qr = qb + w * 16 + lg * 4 + reg;
    qid[reg] = sid[qr];
    lat[reg] = (qr < NLAT);
    mrun[reg] = -1e30f;
    lrun[reg] = 0.f;
  }
  f32x4 oacc[4] = {};

  for (int kt = 0; kt < 16; ++kt) {
    if (!need[kt]) continue;                       // uniform across block
    const int kb = kt * 64;
    __syncthreads();                               // prior-iter LDS reads done

    // stage K: linear LDS dest, XOR-pre-swizzled global source
#pragma unroll
    for (int i = 0; i < 2; ++i) {
      const int ch = tid + 256 * i;                // 0..511
      const int r = ch >> 3, c = ch & 7;
      const int cs = c ^ (r & 7);
      GLOAD_LDS16(kg + hb + (size_t)(kb + r) * HDIM + cs * 8, &sK[ch * 8]);
    }
    // stage V transposed + swizzled (reg -> LDS)
#pragma unroll
    for (int i = 0; i < 2; ++i) {
      const int ch = tid + 256 * i;
      const int s = ch >> 3, dc = ch & 7;
      const short8v vv = *(const short8v*)(vg + hb + (size_t)(kb + s) * HDIM + dc * 8);
#pragma unroll
      for (int jj = 0; jj < 8; ++jj) {
        const int d = dc * 8 + jj;
        sV[d * 64 + (((s >> 3) ^ (d & 7)) * 8) + (s & 7)] = vv[jj];
      }
    }
    __syncthreads();

    // scores: S[16q x 64s] as 4 s-tiles
    f32x4 sc[4];
#pragma unroll
    for (int st = 0; st < 4; ++st) {
      const int srow = st * 16 + li;
      const bf16x8 kf0 = *(const bf16x8*)&sK[srow * 64 + ((lg ^ (srow & 7)) * 8)];
      const bf16x8 kf1 = *(const bf16x8*)&sK[srow * 64 + (((lg + 4) ^ (srow & 7)) * 8)];
      f32x4 z = {0.f, 0.f, 0.f, 0.f};
      z = MFMA16(qf0, kf0, z);
      z = MFMA16(qf1, kf1, z);
      sc[st] = z;
    }
    // mask
#pragma unroll
    for (int st = 0; st < 4; ++st) {
      const int sv = sid[kb + st * 16 + li];
#pragma unroll
      for (int reg = 0; reg < 4; ++reg)
        if (!(lat[reg] || (qid[reg] == sv))) sc[st][reg] = -1e30f;
    }
    // online softmax (row lives across the 16 lanes of a group)
    float ps[4];
#pragma unroll
    for (int reg = 0; reg < 4; ++reg) {
      float mx = fmaxf(fmaxf(sc[0][reg], sc[1][reg]), fmaxf(sc[2][reg], sc[3][reg]));
      mx = fmaxf(mx, __shfl_xor(mx, 1, 64));
      mx = fmaxf(mx, __shfl_xor(mx, 2, 64));
      mx = fmaxf(mx, __shfl_xor(mx, 4, 64));
      mx = fmaxf(mx, __shfl_xor(mx, 8, 64));
      const float mn = fmaxf(mrun[reg], mx);
      const float scale = __expf(mrun[reg] - mn);
      mrun[reg] = mn;
      lrun[reg] *= scale;
#pragma unroll
      for (int dt = 0; dt < 4; ++dt) oacc[dt][reg] *= scale;
      ps[reg] = 0.f;
    }
#pragma unroll
    for (int st = 0; st < 4; ++st) {
#pragma unroll
      for (int reg = 0; reg < 4; ++reg) {
        const float p = __expf(sc[st][reg] - mrun[reg]);
        ps[reg] += p;
        const int row = lg * 4 + reg, scol = st * 16 + li;
        sP[w][row * 64 + (((scol >> 3) ^ (row & 7)) * 8) + (scol & 7)] = f2bf(p);
      }
    }
#pragma unroll
    for (int reg = 0; reg < 4; ++reg) {
      float s4 = ps[reg];
      s4 += __shfl_xor(s4, 1, 64);
      s4 += __shfl_xor(s4, 2, 64);
      s4 += __shfl_xor(s4, 4, 64);
      s4 += __shfl_xor(s4, 8, 64);
      lrun[reg] += s4;
    }
    __syncthreads();                               // P visible (and wave-safe)

    // PV: out[16q x 64d] += P[16q x 64s] * V[64s x 64d]
#pragma unroll
    for (int half = 0; half < 2; ++half) {
      const bf16x8 pa = *(const bf16x8*)&sP[w][li * 64 + (((lg + 4 * half) ^ (li & 7)) * 8)];
#pragma unroll
      for (int dt = 0; dt < 4; ++dt) {
        const int d = dt * 16 + li;
        const bf16x8 vb = *(const bf16x8*)&sV[d * 64 + (((lg + 4 * half) ^ (d & 7)) * 8)];
        oacc[dt] = MFMA16(pa, vb, oacc[dt]);
      }
    }
  }

  // epilogue: divide by denom, write [bt*S + s][h*64 + d] bf16
#pragma unroll
  for (int dt = 0; dt < 4; ++dt) {
#pragma unroll
    for (int reg = 0; reg < 4; ++reg) {
      const int row = qb + w * 16 + lg * 4 + reg;
      const int d = dt * 16 + li;
      const float o = oacc[dt][reg] / lrun[reg];
      ao[((size_t)(bt * SEQ_N + row)) * DMODEL + h * HDIM + d] = f2bf(o);
    }
  }
}

// ---------------------------------------------------------------------------
// Host launcher
// ---------------------------------------------------------------------------
extern "C" void kernel_launch(void* const* d_in, const int* in_sizes, int n_in,
                              void* d_out, int out_size, void* d_ws, size_t ws_size,
                              hipStream_t stream) {
  const float* x  = (const float*)d_in[0];
  const int* ids  = (const int*)d_in[1];
  const float* Wq = (const float*)d_in[2];
  const float* bq = (const float*)d_in[3];
  const float* Wk = (const float*)d_in[4];
  const float* bk = (const float*)d_in[5];
  const float* Wv = (const float*)d_in[6];
  const float* bv = (const float*)d_in[7];
  const float* Wo = (const float*)d_in[8];
  const float* bo = (const float*)d_in[9];
  float* out = (float*)d_out;

  // workspace layout (shorts): 92.3 MB total
  short* ws     = (short*)d_ws;
  short* x_bf   = ws;                          // 8192*1024
  short* wqkv_t = x_bf + 8388608;              // 3072*1024 (B^T: [n][k])
  short* wo_t   = wqkv_t + 3145728;            // 1024*1024 (B^T: [o][k])
  short* q_bf   = wo_t + 1048576;              // [bt][h][s][d] x3 (q,k,v)
  short* k_bf   = q_bf + 8388608;
  short* v_bf   = k_bf + 8388608;
  short* ao_bf  = v_bf + 8388608;              // [bt*s][h*d]

  cvt_plain<<<8192, 256, 0, stream>>>(x, x_bf, 2097152);
  dim3 tg(16, 16);
  cvt_T<<<tg, 256, 0, stream>>>(Wq, wqkv_t);
  cvt_T<<<tg, 256, 0, stream>>>(Wk, wqkv_t + 1048576);
  cvt_T<<<tg, 256, 0, stream>>>(Wv, wqkv_t + 2097152);
  cvt_T<<<tg, 256, 0, stream>>>(Wo, wo_t);

  gemm_bf16<0><<<dim3(24, 64), 256, 0, stream>>>(x_bf, wqkv_t, bq, bk, bv,
                                                 q_bf, nullptr, nullptr);
  attn_kernel<<<dim3(16, NHEADS, BT_N), 256, 0, stream>>>(q_bf, k_bf, v_bf, ids, ao_bf);
  gemm_bf16<1><<<dim3(8, 64), 256, 0, stream>>>(ao_bf, wo_t, nullptr, nullptr, nullptr,
                                                nullptr, bo, out);
}